// Round 11
// baseline (248.148 us; speedup 1.0000x reference)
//
#include <hip/hip_runtime.h>

#define HH 512
#define WW 512
#define ROWS 8
#define TR (ROWS + 2)
#define W4 (WW / 4)             // 128 packed words per gray row
#define CH_STRIDE (HH * WW)
#define IMG_STRIDE (3 * HH * WW)
#define PLANE_W4 (HH * W4)      // 65536 words per gray image
#define NITEM (32 * PLANE_W4)   // 2,097,152 packed words per image set
#define GRAY_BYTES (NITEM * 4)  // 8 MiB per image
#define WS_NEEDED (2u * GRAY_BYTES)

// quantize one channel value: floor(clip(v*255, 0, 255))
__device__ __forceinline__ float quant(float v) {
    return floorf(fminf(fmaxf(v * 255.0f, 0.0f), 255.0f));
}

// pack 4 gray pixels (rounded, cv2 RGB2GRAY weights) into one word.
// KEEP BIT-IDENTICAL to the validated R1/R2 expression.
__device__ __forceinline__ unsigned pack_gray(float4 r, float4 g, float4 b) {
    const unsigned o0 = (unsigned)rintf(0.299f * quant(r.x) + 0.587f * quant(g.x) + 0.114f * quant(b.x));
    const unsigned o1 = (unsigned)rintf(0.299f * quant(r.y) + 0.587f * quant(g.y) + 0.114f * quant(b.y));
    const unsigned o2 = (unsigned)rintf(0.299f * quant(r.z) + 0.587f * quant(g.z) + 0.114f * quant(b.z));
    const unsigned o3 = (unsigned)rintf(0.299f * quant(r.w) + 0.587f * quant(g.w) + 0.114f * quant(b.w));
    return o0 | (o1 << 8) | (o2 << 16) | (o3 << 24);
}

// 4 rounded sobel-avg values (exact integer path) for word w4v of LDS row lr
__device__ __forceinline__ void sobel4(const unsigned* __restrict__ g, int lr, int w4v, int out[4]) {
    const unsigned c0 = g[(lr - 1) * W4 + w4v];
    const unsigned c1 = g[lr * W4 + w4v];
    const unsigned c2 = g[(lr + 1) * W4 + w4v];
    const unsigned lw = g[lr * W4 + (w4v == 0 ? 0 : w4v - 1)];
    const unsigned rw = g[lr * W4 + (w4v == W4 - 1 ? W4 - 1 : w4v + 1)];

    int gx[6];
    gx[0] = (w4v == 0) ? (int)((c1 >> 8) & 255u) : (int)(lw >> 24);
    gx[1] = (int)(c1 & 255u);
    gx[2] = (int)((c1 >> 8) & 255u);
    gx[3] = (int)((c1 >> 16) & 255u);
    gx[4] = (int)(c1 >> 24);
    gx[5] = (w4v == W4 - 1) ? (int)((c1 >> 16) & 255u) : (int)(rw & 255u);

#pragma unroll
    for (int j = 0; j < 4; ++j) {
        const int sx = __builtin_abs(gx[j + 2] - gx[j]);
        const int sy = __builtin_abs((int)((c2 >> (8 * j)) & 255u) - (int)((c0 >> (8 * j)) & 255u));
        const int s = sx + sy;
        out[j] = (s >> 1) + ((s & 1) & ((s >> 1) & 1));   // round-half-even of s/2
    }
}

// ---------------- pass 1: copy-shaped gray conversion ----------------
// Pure streaming: 6 coalesced float4 loads -> 2 packed word stores per item.
// No LDS, no barriers, ~full occupancy. This is the BW probe.
__global__ __launch_bounds__(256) void gray_kernel(
    const float* __restrict__ pred, const float* __restrict__ gt_,
    unsigned* __restrict__ gP, unsigned* __restrict__ gT)
{
    for (int g = blockIdx.x * 256 + threadIdx.x; g < NITEM; g += 2048 * 256) {
        const int b  = g >> 16;          // image index
        const int f4 = g & 65535;        // float4 index within a plane
        const float4* Pp = reinterpret_cast<const float4*>(pred + (size_t)b * IMG_STRIDE);
        const float4* Tp = reinterpret_cast<const float4*>(gt_  + (size_t)b * IMG_STRIDE);
        const float4 pr = Pp[f4], pg = Pp[PLANE_W4 + f4], pb = Pp[2 * PLANE_W4 + f4];
        const float4 tr = Tp[f4], tg = Tp[PLANE_W4 + f4], tb = Tp[2 * PLANE_W4 + f4];
        gP[g] = pack_gray(pr, pg, pb);
        gT[g] = pack_gray(tr, tg, tb);
    }
}

// ---------------- pass 2: sobel + reduce on packed gray ----------------
__global__ __launch_bounds__(256) void sobel2_kernel(
    const unsigned* __restrict__ gP, const unsigned* __restrict__ gT,
    float* __restrict__ out)
{
    __shared__ unsigned gp[TR * W4];
    __shared__ unsigned gq[TR * W4];
    __shared__ int red[4];

    const int b     = blockIdx.x >> 6;
    const int chunk = blockIdx.x & 63;
    const int r0    = chunk * ROWS;

    for (int i = threadIdx.x; i < TR * W4; i += 256) {
        const int lr = i >> 7, w = i & 127;
        int gr = r0 - 1 + lr;
        gr = (gr < 0) ? 1 : ((gr > HH - 1) ? 2 * (HH - 1) - gr : gr);
        gp[i] = gP[b * PLANE_W4 + gr * W4 + w];
        gq[i] = gT[b * PLANE_W4 + gr * W4 + w];
    }
    __syncthreads();

    int acc = 0;
    for (int idx = threadIdx.x; idx < ROWS * W4; idx += 256) {
        const int lr = (idx >> 7) + 1;
        const int w  = idx & 127;
        int sp[4], st[4];
        sobel4(gp, lr, w, sp);
        sobel4(gq, lr, w, st);
#pragma unroll
        for (int t2 = 0; t2 < 4; ++t2)
            acc += __builtin_abs(sp[t2] - st[t2]);
    }

    for (int off = 32; off > 0; off >>= 1)
        acc += __shfl_down(acc, off, 64);
    const int lane = threadIdx.x & 63, wid = threadIdx.x >> 6;
    if (lane == 0) red[wid] = acc;
    __syncthreads();
    if (threadIdx.x == 0) {
        const int s = red[0] + red[1] + red[2] + red[3];
        atomicAdd(out, (float)s * (1.0f / (255.0f * 32.0f * 512.0f * 512.0f)));
    }
}

// ---------------- fallback: validated R2 fused kernel (ws too small) ----------------
__global__ __launch_bounds__(256, 8) void sobel_fused_kernel(
    const float* __restrict__ pred, const float* __restrict__ gt_,
    float* __restrict__ out)
{
    __shared__ unsigned gp[TR * W4];
    __shared__ unsigned gq[TR * W4];
    __shared__ int red[4];

    const int b     = blockIdx.x >> 6;
    const int chunk = blockIdx.x & 63;
    const int r0    = chunk * ROWS;
    const float* P = pred + (size_t)b * IMG_STRIDE;
    const float* T = gt_  + (size_t)b * IMG_STRIDE;

    for (int i4 = threadIdx.x; i4 < TR * W4; i4 += 256) {
        const int lr = i4 >> 7, wq = i4 & 127;
        int gr = r0 - 1 + lr;
        gr = (gr < 0) ? 1 : ((gr > HH - 1) ? 2 * (HH - 1) - gr : gr);
        const float4 pr = reinterpret_cast<const float4*>(P + 0 * CH_STRIDE + gr * WW)[wq];
        const float4 pg = reinterpret_cast<const float4*>(P + 1 * CH_STRIDE + gr * WW)[wq];
        const float4 pb = reinterpret_cast<const float4*>(P + 2 * CH_STRIDE + gr * WW)[wq];
        gp[i4] = pack_gray(pr, pg, pb);
        const float4 tr = reinterpret_cast<const float4*>(T + 0 * CH_STRIDE + gr * WW)[wq];
        const float4 tg = reinterpret_cast<const float4*>(T + 1 * CH_STRIDE + gr * WW)[wq];
        const float4 tb = reinterpret_cast<const float4*>(T + 2 * CH_STRIDE + gr * WW)[wq];
        gq[i4] = pack_gray(tr, tg, tb);
    }
    __syncthreads();

    int acc = 0;
    for (int idx = threadIdx.x; idx < ROWS * W4; idx += 256) {
        const int lr = (idx >> 7) + 1, w = idx & 127;
        int sp[4], st[4];
        sobel4(gp, lr, w, sp);
        sobel4(gq, lr, w, st);
#pragma unroll
        for (int t2 = 0; t2 < 4; ++t2)
            acc += __builtin_abs(sp[t2] - st[t2]);
    }

    for (int off = 32; off > 0; off >>= 1)
        acc += __shfl_down(acc, off, 64);
    const int lane = threadIdx.x & 63, wid = threadIdx.x >> 6;
    if (lane == 0) red[wid] = acc;
    __syncthreads();
    if (threadIdx.x == 0) {
        const int s = red[0] + red[1] + red[2] + red[3];
        atomicAdd(out, (float)s * (1.0f / (255.0f * 32.0f * 512.0f * 512.0f)));
    }
}

extern "C" void kernel_launch(void* const* d_in, const int* in_sizes, int n_in,
                              void* d_out, int out_size, void* d_ws, size_t ws_size,
                              hipStream_t stream) {
    const float* y_pred = (const float*)d_in[0];
    const float* y_true = (const float*)d_in[1];
    float* out = (float*)d_out;

    hipMemsetAsync(out, 0, out_size * sizeof(float), stream);

    if (ws_size >= WS_NEEDED) {
        unsigned* gP = (unsigned*)d_ws;
        unsigned* gT = gP + NITEM;
        gray_kernel<<<2048, 256, 0, stream>>>(y_pred, y_true, gP, gT);
        sobel2_kernel<<<32 * 64, 256, 0, stream>>>(gP, gT, out);
    } else {
        sobel_fused_kernel<<<32 * 64, 256, 0, stream>>>(y_pred, y_true, out);
    }
}

// Round 12
// 245.566 us; speedup vs baseline: 1.0105x; 1.0105x over previous
//
#include <hip/hip_runtime.h>

#define HH 512
#define WW 512
#define ROWS 8
#define TR (ROWS + 2)
#define W4 (WW / 4)
#define CH_STRIDE (HH * WW)
#define IMG_STRIDE (3 * HH * WW)
#define NCHUNK (HH / ROWS)            // 64
#define COPY_N4 (32 * IMG_STRIDE / 4) // 6,291,456 float4s = 100.66 MB

// quantize one channel value: floor(clip(v*255, 0, 255))
__device__ __forceinline__ float quant(float v) {
    return floorf(fminf(fmaxf(v * 255.0f, 0.0f), 255.0f));
}

// pack 4 gray pixels (rounded, cv2 RGB2GRAY weights) into one word.
// KEEP BIT-IDENTICAL to the validated R1/R2 expression.
__device__ __forceinline__ unsigned pack_gray(float4 r, float4 g, float4 b) {
    const unsigned o0 = (unsigned)rintf(0.299f * quant(r.x) + 0.587f * quant(g.x) + 0.114f * quant(b.x));
    const unsigned o1 = (unsigned)rintf(0.299f * quant(r.y) + 0.587f * quant(g.y) + 0.114f * quant(b.y));
    const unsigned o2 = (unsigned)rintf(0.299f * quant(r.z) + 0.587f * quant(g.z) + 0.114f * quant(b.z));
    const unsigned o3 = (unsigned)rintf(0.299f * quant(r.w) + 0.587f * quant(g.w) + 0.114f * quant(b.w));
    return o0 | (o1 << 8) | (o2 << 16) | (o3 << 24);
}

// 4 rounded sobel-avg values (exact integer path) for word w4v of LDS row lr
__device__ __forceinline__ void sobel4(const unsigned* __restrict__ g, int lr, int w4v, int out[4]) {
    const unsigned c0 = g[(lr - 1) * W4 + w4v];
    const unsigned c1 = g[lr * W4 + w4v];
    const unsigned c2 = g[(lr + 1) * W4 + w4v];
    const unsigned lw = g[lr * W4 + (w4v == 0 ? 0 : w4v - 1)];
    const unsigned rw = g[lr * W4 + (w4v == W4 - 1 ? W4 - 1 : w4v + 1)];

    int gx[6];
    gx[0] = (w4v == 0) ? (int)((c1 >> 8) & 255u) : (int)(lw >> 24);
    gx[1] = (int)(c1 & 255u);
    gx[2] = (int)((c1 >> 8) & 255u);
    gx[3] = (int)((c1 >> 16) & 255u);
    gx[4] = (int)(c1 >> 24);
    gx[5] = (w4v == W4 - 1) ? (int)((c1 >> 16) & 255u) : (int)(rw & 255u);

#pragma unroll
    for (int j = 0; j < 4; ++j) {
        const int sx = __builtin_abs(gx[j + 2] - gx[j]);
        const int sy = __builtin_abs((int)((c2 >> (8 * j)) & 255u) - (int)((c0 >> (8 * j)) & 255u));
        const int s = sx + sy;
        out[j] = (s >> 1) + ((s & 1) & ((s >> 1) & 1));   // round-half-even of s/2
    }
}

// ---------------- m13-pattern copy probe: known-good BW reference ----------------
// Pure grid-stride float4 copy, 1:1 read:write. If this runs ≈6 TB/s the memory
// system is healthy and the 2.45 TB/s wall is kernel-shape-specific; if it runs
// ≈2.5 TB/s the platform ceiling is real.
__global__ __launch_bounds__(256) void copy_probe(
    const float4* __restrict__ src, float4* __restrict__ dst, int n4)
{
    for (int i = blockIdx.x * 256 + threadIdx.x; i < n4; i += 2048 * 256)
        dst[i] = src[i];
}

// ---------------- validated R2 fused kernel (output path, absmax 0) ----------------
__global__ __launch_bounds__(256, 8) void sobel_fused_kernel(
    const float* __restrict__ pred, const float* __restrict__ gt_,
    float* __restrict__ out)
{
    __shared__ unsigned gp[TR * W4];
    __shared__ unsigned gq[TR * W4];
    __shared__ int red[4];

    const int b     = blockIdx.x >> 6;
    const int chunk = blockIdx.x & (NCHUNK - 1);
    const int r0    = chunk * ROWS;
    const float* P = pred + (size_t)b * IMG_STRIDE;
    const float* T = gt_  + (size_t)b * IMG_STRIDE;

    for (int i4 = threadIdx.x; i4 < TR * W4; i4 += 256) {
        const int lr = i4 >> 7, wq = i4 & 127;
        int gr = r0 - 1 + lr;
        gr = (gr < 0) ? 1 : ((gr > HH - 1) ? 2 * (HH - 1) - gr : gr);
        const float4 pr = reinterpret_cast<const float4*>(P + 0 * CH_STRIDE + gr * WW)[wq];
        const float4 pg = reinterpret_cast<const float4*>(P + 1 * CH_STRIDE + gr * WW)[wq];
        const float4 pb = reinterpret_cast<const float4*>(P + 2 * CH_STRIDE + gr * WW)[wq];
        gp[i4] = pack_gray(pr, pg, pb);
        const float4 tr = reinterpret_cast<const float4*>(T + 0 * CH_STRIDE + gr * WW)[wq];
        const float4 tg = reinterpret_cast<const float4*>(T + 1 * CH_STRIDE + gr * WW)[wq];
        const float4 tb = reinterpret_cast<const float4*>(T + 2 * CH_STRIDE + gr * WW)[wq];
        gq[i4] = pack_gray(tr, tg, tb);
    }
    __syncthreads();

    int acc = 0;
    for (int idx = threadIdx.x; idx < ROWS * W4; idx += 256) {
        const int lr = (idx >> 7) + 1, w = idx & 127;
        int sp[4], st[4];
        sobel4(gp, lr, w, sp);
        sobel4(gq, lr, w, st);
#pragma unroll
        for (int t2 = 0; t2 < 4; ++t2)
            acc += __builtin_abs(sp[t2] - st[t2]);
    }

    for (int off = 32; off > 0; off >>= 1)
        acc += __shfl_down(acc, off, 64);
    const int lane = threadIdx.x & 63, wid = threadIdx.x >> 6;
    if (lane == 0) red[wid] = acc;
    __syncthreads();
    if (threadIdx.x == 0) {
        const int s = red[0] + red[1] + red[2] + red[3];
        atomicAdd(out, (float)s * (1.0f / (255.0f * 32.0f * 512.0f * 512.0f)));
    }
}

extern "C" void kernel_launch(void* const* d_in, const int* in_sizes, int n_in,
                              void* d_out, int out_size, void* d_ws, size_t ws_size,
                              hipStream_t stream) {
    const float* y_pred = (const float*)d_in[0];
    const float* y_true = (const float*)d_in[1];
    float* out = (float*)d_out;

    hipMemsetAsync(out, 0, out_size * sizeof(float), stream);

    // BW probe (diagnostic only; result unused). Sized to what ws allows.
    const int n4 = (int)((ws_size / sizeof(float4) < (size_t)COPY_N4)
                             ? ws_size / sizeof(float4) : (size_t)COPY_N4);
    if (n4 > 0)
        copy_probe<<<2048, 256, 0, stream>>>(
            reinterpret_cast<const float4*>(y_pred), (float4*)d_ws, n4);

    sobel_fused_kernel<<<32 * NCHUNK, 256, 0, stream>>>(y_pred, y_true, out);
}